// Round 6
// baseline (96.062 us; speedup 1.0000x reference)
//
#include <hip/hip_runtime.h>
#include <math.h>

namespace {
constexpr int N  = 32;
constexpr int NB = 2048;
constexpr int T  = 1024;
constexpr float DT_  = 0.1f;
constexpr float RMIN = 1.0e5f, RMAX = 1.0e7f;
constexpr float CMIN = 1.0e-7f, CMAX = 1.0e-4f;
constexpr int NSEG = 4;              // 4 x 256-timestep segments per wave

typedef float f4 __attribute__((ext_vector_type(4)));   // native vector for nt builtins
}

// Pass 1: beta once, transposed to [n][t] (128 KB, stays L2-resident).
__global__ void __launch_bounds__(256)
beta_init(const float* __restrict__ Rp, const float* __restrict__ Cp,
          const float* __restrict__ noise_R, const float* __restrict__ noise_C,
          const float* __restrict__ mu, float* __restrict__ betaT)
{
    const int i = blockIdx.x * 256 + threadIdx.x;      // i = t*N + n
    const float R_true = (RMAX - RMIN) / (1.0f + expf(-Rp[0])) + RMIN;
    const float C_true = (CMAX - CMIN) / (1.0f + expf(-Cp[0])) + CMIN;
    const float rc = mu[i] * (R_true * noise_R[i]) * (C_true * noise_C[i]);
    const int t = i >> 5, n = i & (N - 1);
    betaT[n * T + t] = rc / (rc + DT_);
}

// Pass 2: one wave per (n, nb) sequence. No LDS, no barrier. Scans run in two
// 2-segment halves so the first half's stores issue while the second half's
// shuffle-scan is still in flight.
__global__ void __launch_bounds__(256, 8)
lf_scan(const float* __restrict__ x,
        const float* __restrict__ betaT,
        const float* __restrict__ memory0,
        float* __restrict__ out)
{
    const int tid  = threadIdx.x;
    const int w    = tid >> 6;
    const int lane = tid & 63;
    const int bid  = blockIdx.x;
    const int n    = bid >> 9;                          // 512 blocks per n
    const int nb   = ((bid & 511) << 2) + w;            // 4 waves per block

    const size_t base = ((size_t)n * NB + (size_t)nb) * (size_t)T;
    const f4* __restrict__ xv = reinterpret_cast<const f4*>(x + base);
    f4*       __restrict__ ov = reinterpret_cast<f4*>(out + base);
    const f4* __restrict__ bv = reinterpret_cast<const f4*>(betaT + n * T);

    // ---- issue carry-in + all streaming loads up front ----
    float ms = memory0[n * NB + nb];                    // wave-uniform, early
    f4 X[NSEG], B[NSEG];
    #pragma unroll
    for (int s = 0; s < NSEG; ++s) X[s] = __builtin_nontemporal_load(&xv[s * 64 + lane]);
    #pragma unroll
    for (int s = 0; s < NSEG; ++s) B[s] = bv[s * 64 + lane];

    // Process segments in pairs: compose+scan (2-way ILP) -> regen -> store,
    // so pair-0 stores overlap pair-1 scan work.
    #pragma unroll
    for (int h = 0; h < 2; ++h) {
        float P[2], Q[2];
        #pragma unroll
        for (int k = 0; k < 2; ++k) {
            const int s = 2 * h + k;
            const f4 b  = B[s];
            const f4 xc = X[s];
            float p = b.x, q = (1.0f - b.x) * xc.x;
            q = fmaf(b.y, q, (1.0f - b.y) * xc.y); p *= b.y;
            q = fmaf(b.z, q, (1.0f - b.z) * xc.z); p *= b.z;
            q = fmaf(b.w, q, (1.0f - b.w) * xc.w); p *= b.w;
            P[k] = p; Q[k] = q;
        }

        // two independent 64-lane inclusive scans, interleaved
        #pragma unroll
        for (int d = 1; d < 64; d <<= 1) {
            float Pin[2], Qin[2];
            #pragma unroll
            for (int k = 0; k < 2; ++k) {
                Pin[k] = __shfl_up(P[k], (unsigned)d, 64);
                Qin[k] = __shfl_up(Q[k], (unsigned)d, 64);
            }
            #pragma unroll
            for (int k = 0; k < 2; ++k) {
                if (lane >= d) {
                    Q[k] = fmaf(P[k], Qin[k], Q[k]);
                    P[k] = P[k] * Pin[k];
                }
            }
        }

        // regen pre-update outputs + store immediately; carry across segments
        #pragma unroll
        for (int k = 0; k < 2; ++k) {
            const int s = 2 * h + k;
            const float Pe  = __shfl_up(P[k], 1u, 64);
            const float Qe  = __shfl_up(Q[k], 1u, 64);
            const float P63 = __shfl(P[k], 63, 64);
            const float Q63 = __shfl(Q[k], 63, 64);
            float me = (lane == 0) ? ms : fmaf(Pe, ms, Qe);

            const f4 b  = B[s];
            const f4 xc = X[s];
            f4 o;
            o.x = me; me = fmaf(b.x, me - xc.x, xc.x);
            o.y = me; me = fmaf(b.y, me - xc.y, xc.y);
            o.z = me; me = fmaf(b.z, me - xc.z, xc.z);
            o.w = me;
            __builtin_nontemporal_store(o, &ov[s * 64 + lane]);

            ms = fmaf(P63, ms, Q63);                    // carry to next segment
        }
    }
}

extern "C" void kernel_launch(void* const* d_in, const int* in_sizes, int n_in,
                              void* d_out, int out_size, void* d_ws, size_t ws_size,
                              hipStream_t stream) {
    const float* x   = (const float*)d_in[0];
    const float* Rp  = (const float*)d_in[1];
    const float* Cp  = (const float*)d_in[2];
    const float* nR  = (const float*)d_in[3];
    const float* nC  = (const float*)d_in[4];
    const float* muv = (const float*)d_in[5];
    const float* m0  = (const float*)d_in[6];
    float* out   = (float*)d_out;
    float* betaT = (float*)d_ws;                        // T*N floats = 128 KB

    beta_init<<<dim3((T * N) / 256), 256, 0, stream>>>(Rp, Cp, nR, nC, muv, betaT);
    lf_scan<<<dim3(N * (NB / 4)), 256, 0, stream>>>(x, betaT, m0, out);
}